// Round 10
// baseline (462.126 us; speedup 1.0000x reference)
//
#include <hip/hip_runtime.h>
#include <hip/hip_bf16.h>
#include <cstddef>

#define Dm   256
#define Hh   8
#define Bb   16
#define Qq   512
#define Ss   15360
#define TOK  (Bb*Qq)          // 8192
#define VROWS (Bb*Ss)         // 245760
#define EPSf 1e-5f
#define SCALEf 0.17677669529663687f

typedef __attribute__((ext_vector_type(8))) short bf16x8;
typedef __attribute__((ext_vector_type(4))) float f32x4;

__device__ __forceinline__ unsigned short rne_bf16(float f) {
    unsigned int u = __builtin_bit_cast(unsigned int, f);
    u += 0x7fffu + ((u >> 16) & 1u);
    return (unsigned short)(u >> 16);
}
__device__ __forceinline__ float bf2f(unsigned short u) {
    return __builtin_bit_cast(float, (unsigned int)u << 16);
}

// ---------------------------------------------------------------------------
// One-shot weight conversion: 9 fp32 weight mats -> contiguous bf16 region,
// + ca bias concat. Grid = 1089 blocks x 256 thr (1088*256 float4 = exact).
// ---------------------------------------------------------------------------
struct WcArgs { const float* src[9]; };

__global__ __launch_bounds__(256) void wconv_kernel(
    WcArgs a, unsigned short* __restrict__ dst,
    const float* __restrict__ offb, const float* __restrict__ attnb,
    float* __restrict__ bias_oa)
{
    if (blockIdx.x == 1088) {
        int t = threadIdx.x;
        bias_oa[t] = (t < 128) ? offb[t] : attnb[t - 128];
        return;
    }
    int g = blockIdx.x * 256 + threadIdx.x;   // float4 index
    const int pre[10] = {0, 49152, 65536, 73728, 81920, 98304, 114688, 147456, 212992, 278528};
    int seg = 0;
    #pragma unroll
    for (int s2 = 1; s2 < 9; ++s2) seg += (g >= pre[s2]);
    float4 f = reinterpret_cast<const float4*>(a.src[seg])[g - pre[seg]];
    ushort4 o;
    o.x = rne_bf16(f.x); o.y = rne_bf16(f.y);
    o.z = rne_bf16(f.z); o.w = rne_bf16(f.w);
    reinterpret_cast<ushort4*>(dst)[g] = o;
}

// ---------------------------------------------------------------------------
// MSDA aggregation over RAW fp32 src (projection commuted to after sampling):
//   agg[h][mod*8192+tok][c] = sum_{l,p} attn * (w0*src[i0,c] + w1*src[i1,c])
//   sumw[h][mod*8192+tok]   = sum_{l,p} attn * (w0m + w1m)
// One block (256 thr) per (mod, tok); 4 lane-groups x 2 heads each; full-row
// float4 coalesced gathers; fp32 accumulate. No LDS conflicts, no MFMA.
// ---------------------------------------------------------------------------
__global__ __launch_bounds__(256) void msda_agg_kernel(
    const float* __restrict__ vsrc, const float* __restrict__ asrc,
    const float* __restrict__ vloc, const float* __restrict__ vattn,
    const float* __restrict__ aloc, const float* __restrict__ aattn,
    unsigned short* __restrict__ agg, float* __restrict__ sumw)
{
    __shared__ float sl[128], sa[128];
    const int blk = blockIdx.x;              // mod*8192 + tok
    const int mod = blk >> 13, tok = blk & 8191, b = tok >> 9;
    const float* loc  = mod ? aloc  : vloc;
    const float* attn = mod ? aattn : vattn;
    const float* src  = (mod ? asrc : vsrc) + (size_t)b * Ss * 256;
    const int t = threadIdx.x;
    if (t < 128) sl[t] = loc[(size_t)tok * 128 + t];
    else         sa[t - 128] = attn[(size_t)tok * 128 + (t - 128)];
    __syncthreads();
    const int g = t >> 6, lane = t & 63;
    const int Tt[4]   = {8192, 4096, 2048, 1024};
    const int LSIc[4] = {0, 8192, 12288, 14336};
    #pragma unroll
    for (int hh = 0; hh < 2; ++hh) {
        const int h = g * 2 + hh;
        float4 acc = {0.f, 0.f, 0.f, 0.f};
        float sw = 0.f;
        #pragma unroll
        for (int l = 0; l < 4; ++l) {
            const float* vl = src + (size_t)LSIc[l] * 256 + lane * 4;
            const int T = Tt[l];
            #pragma unroll
            for (int p = 0; p < 4; ++p) {
                const int e = h * 16 + l * 4 + p;
                const float lc = sl[e], at = sa[e];
                const float x = lc * (float)T - 0.5f;
                const float x0 = floorf(x);
                const float w = x - x0;
                const int i0 = (int)x0;
                const int i1 = i0 + 1;
                const float w0 = (i0 >= 0 && i0 < T) ? at * (1.f - w) : 0.f;
                const float w1 = (i1 >= 0 && i1 < T) ? at * w : 0.f;
                sw += w0 + w1;
                const int i0c = min(max(i0, 0), T - 1);
                const int i1c = min(max(i1, 0), T - 1);
                float4 g0 = *reinterpret_cast<const float4*>(vl + (size_t)i0c * 256);
                float4 g1 = *reinterpret_cast<const float4*>(vl + (size_t)i1c * 256);
                acc.x += w0 * g0.x + w1 * g1.x;
                acc.y += w0 * g0.y + w1 * g1.y;
                acc.z += w0 * g0.z + w1 * g1.z;
                acc.w += w0 * g0.w + w1 * g1.w;
            }
        }
        const size_t row = (size_t)h * 16384 + blk;
        ushort4 o;
        o.x = rne_bf16(acc.x); o.y = rne_bf16(acc.y);
        o.z = rne_bf16(acc.z); o.w = rne_bf16(acc.w);
        *reinterpret_cast<ushort4*>(&agg[row * 256 + lane * 4]) = o;
        if (lane == 0) sumw[row] = sw;
    }
}

// ---------------------------------------------------------------------------
// Block-diagonal projection of agg: samp[r][h*32+c] = agg[h][r] @ Wv[h-slice]^T
//   + bv[h*32+c] * sumw[h][r].  256 thr = 4 waves, wave = 16 rows x 32 cols.
// Swapped-operand MFMA (W rows as A-op) -> packed ushort4 stores (v4-verified
// fragment math). W slice kept in registers (16 frags), A read from global.
// Grid = (16384/64, 8 heads).
// ---------------------------------------------------------------------------
__global__ __launch_bounds__(256) void agg_proj_kernel(
    const unsigned short* __restrict__ agg, const float* __restrict__ sumw,
    const unsigned short* __restrict__ W, const float* __restrict__ bias,
    unsigned short* __restrict__ samp)
{
    const int tid = threadIdx.x, wv = tid >> 6, lane = tid & 63;
    const int l15 = lane & 15, l4 = lane >> 4;
    const int h = blockIdx.y;
    const int bm = blockIdx.x * 64;

    // W fragments: rows h*32 + n*16 + l15, k chunk kc*32 + l4*8
    bf16x8 wf[2][8];
    #pragma unroll
    for (int n = 0; n < 2; ++n)
        #pragma unroll
        for (int kc = 0; kc < 8; ++kc)
            wf[n][kc] = *reinterpret_cast<const bf16x8*>(
                &W[(size_t)(h * 32 + n * 16 + l15) * 256 + kc * 32 + l4 * 8]);
    float4 bv[2];
    #pragma unroll
    for (int n = 0; n < 2; ++n)
        bv[n] = *reinterpret_cast<const float4*>(&bias[h * 32 + n * 16 + l4 * 4]);

    const size_t slab = (size_t)h * 16384;
    const int r0 = bm + wv * 16;                      // wave's first row
    const unsigned short* ap = &agg[(slab + r0 + l15) * 256 + l4 * 8];
    const float srow = sumw[slab + r0 + l15];

    f32x4 acc[2] = {};
    #pragma unroll
    for (int kc = 0; kc < 8; ++kc) {
        bf16x8 af = *reinterpret_cast<const bf16x8*>(ap + kc * 32);
        acc[0] = __builtin_amdgcn_mfma_f32_16x16x32_bf16(wf[0][kc], af, acc[0], 0, 0, 0);
        acc[1] = __builtin_amdgcn_mfma_f32_16x16x32_bf16(wf[1][kc], af, acc[1], 0, 0, 0);
    }
    // store: row = r0 + l15, col = h*32 + n*16 + l4*4 + v (packed 8B)
    #pragma unroll
    for (int n = 0; n < 2; ++n) {
        ushort4 o;
        o.x = rne_bf16(acc[n][0] + bv[n].x * srow);
        o.y = rne_bf16(acc[n][1] + bv[n].y * srow);
        o.z = rne_bf16(acc[n][2] + bv[n].z * srow);
        o.w = rne_bf16(acc[n][3] + bv[n].w * srow);
        *reinterpret_cast<ushort4*>(
            &samp[(size_t)(r0 + l15) * 256 + h * 32 + n * 16 + l4 * 4]) = o;
    }
}

// ---------------------------------------------------------------------------
// Generic MFMA GEMM: C[M,N] = A[M,K] @ W[N,K](bf16)^T + bias, opt. ReLU.
// 512 thr = 8 waves (2x4), wave tile (BM/2)x(BN/4), 16x16x32 bf16, BK=32.
// ABF: A bf16; ADD: A += A2 (fp32); OBF: bf16 out; SPLITA: A/Ab at Msplit.
// ---------------------------------------------------------------------------
template<int BM, int BN, bool RELU, bool ABF, bool OBF, bool ADD, bool SPLITA>
__global__ __launch_bounds__(512) void gemm_mfma_kernel(
    const void* __restrict__ Ap, const void* __restrict__ Ap2,
    const float* __restrict__ A2,
    const unsigned short* __restrict__ W,
    const float* __restrict__ bias, void* __restrict__ Cp,
    int M, int N, int K, int Msplit)
{
    constexpr int MI = BM / 32;
    constexpr int NI = BN / 64;
    __shared__ unsigned short As[BM * 32];
    __shared__ unsigned short Bs[BN * 32];
    const int tid = threadIdx.x, wid = tid >> 6, lane = tid & 63;
    const int wr = wid >> 2, wc = wid & 3;
    const int bm = blockIdx.x * BM, bn = blockIdx.y * BN;
    const int l15 = lane & 15, l4 = lane >> 4;
    const void* Ause = Ap;
    int bmA = bm;
    if (SPLITA && bm >= Msplit) { Ause = Ap2; bmA = bm - Msplit; }
    f32x4 acc[MI][NI] = {};

    for (int k0 = 0; k0 < K; k0 += 32) {
        __syncthreads();
        if (ABF) {
            const unsigned short* A = (const unsigned short*)Ause;
            constexpr int CH = BM * 4;
            #pragma unroll
            for (int i = 0; i < (CH + 511) / 512; ++i) {
                int idx = i * 512 + tid;
                if ((CH % 512) && idx >= CH) break;
                int row = idx >> 2, c = idx & 3;
                int4 a4 = *reinterpret_cast<const int4*>(&A[(size_t)(bmA + row) * K + k0 + c * 8]);
                *reinterpret_cast<int4*>(reinterpret_cast<char*>(As)
                    + row * 64 + ((c ^ (row & 3)) << 4)) = a4;
            }
        } else {
            const float* A = (const float*)Ause;
            constexpr int CH = BM * 8;
            #pragma unroll
            for (int i = 0; i < CH / 512; ++i) {
                int idx = i * 512 + tid;
                int row = idx >> 3, c4 = idx & 7;
                size_t g = (size_t)(bmA + row) * K + k0 + c4 * 4;
                float4 a4 = *reinterpret_cast<const float4*>(&A[g]);
                if (ADD) {
                    float4 b4 = *reinterpret_cast<const float4*>(
                        &A2[(size_t)(bm + row) * K + k0 + c4 * 4]);
                    a4.x += b4.x; a4.y += b4.y; a4.z += b4.z; a4.w += b4.w;
                }
                ushort4 u;
                u.x = rne_bf16(a4.x); u.y = rne_bf16(a4.y);
                u.z = rne_bf16(a4.z); u.w = rne_bf16(a4.w);
                *reinterpret_cast<ushort4*>(reinterpret_cast<char*>(As)
                    + row * 64 + (((c4 >> 1) ^ (row & 3)) << 4) + (c4 & 1) * 8) = u;
            }
        }
        {
            constexpr int CH = BN * 4;
            #pragma unroll
            for (int i = 0; i < CH / 512; ++i) {
                int idx = i * 512 + tid;
                int row = idx >> 2, c = idx & 3;
                int4 w4 = *reinterpret_cast<const int4*>(&W[(size_t)(bn + row) * K + k0 + c * 8]);
                *reinterpret_cast<int4*>(reinterpret_cast<char*>(Bs)
                    + row * 64 + ((c ^ (row & 3)) << 4)) = w4;
            }
        }
        __syncthreads();
        bf16x8 af[MI], bfr[NI];
        #pragma unroll
        for (int i = 0; i < MI; ++i) {
            int r = wr * (BM / 2) + i * 16 + l15;
            af[i] = *reinterpret_cast<const bf16x8*>(
                reinterpret_cast<const char*>(As) + r * 64 + ((l4 ^ (r & 3)) << 4));
        }
        #pragma unroll
        for (int j = 0; j < NI; ++j) {
            int r = wc * (BN / 4) + j * 16 + l15;
            bfr[j] = *reinterpret_cast<const bf16x8*>(
                reinterpret_cast<const char*>(Bs) + r * 64 + ((l4 ^ (r & 3)) << 4));
        }
        #pragma unroll
        for (int i = 0; i < MI; ++i)
            #pragma unroll
            for (int j = 0; j < NI; ++j)
                acc[i][j] = __builtin_amdgcn_mfma_f32_16x16x32_bf16(
                    af[i], bfr[j], acc[i][j], 0, 0, 0);
    }
    #pragma unroll
    for (int j = 0; j < NI; ++j) {
        int col = bn + wc * (BN / 4) + j * 16 + l15;
        float bv = bias[col];
        #pragma unroll
        for (int i = 0; i < MI; ++i) {
            int row0 = bm + wr * (BM / 2) + i * 16 + l4 * 4;
            #pragma unroll
            for (int v = 0; v < 4; ++v) {
                float val = acc[i][j][v] + bv;
                if (RELU) val = fmaxf(val, 0.f);
                if (OBF)
                    ((unsigned short*)Cp)[(size_t)(row0 + v) * N + col] = rne_bf16(val);
                else
                    ((float*)Cp)[(size_t)(row0 + v) * N + col] = val;
            }
        }
    }
}

// ---------------------------------------------------------------------------
// MFMA GEMM (bf16 A, N=256=BN) with fused residual-add + LayerNorm epilogue.
// out = LN(res + A@W^T + bias) * lnw + lnb   (fp32 out).
// DUAL: rows >= M/2 go to out1 with res/row rebased (video/audio batch).
// ---------------------------------------------------------------------------
template<int BM, bool DUAL>
__global__ __launch_bounds__(512) void gemm_ln_kernel(
    const unsigned short* __restrict__ A,
    const unsigned short* __restrict__ W,
    const float* __restrict__ bias,
    const float* __restrict__ res,
    const float* __restrict__ lnw, const float* __restrict__ lnb,
    float* __restrict__ out0, float* __restrict__ out1,
    int M, int K)
{
    constexpr int MI = BM / 32;
    constexpr int NI = 4;               // BN = 256
    __shared__ unsigned short As[BM * 32];
    __shared__ unsigned short Bs[256 * 32];
    __shared__ float redS[BM][4];
    __shared__ float redQ[BM][4];
    const int tid = threadIdx.x, wid = tid >> 6, lane = tid & 63;
    const int wr = wid >> 2, wc = wid & 3;
    const int bm = blockIdx.x * BM;
    const int l15 = lane & 15, l4 = lane >> 4;
    f32x4 acc[MI][NI] = {};

    for (int k0 = 0; k0 < K; k0 += 32) {
        __syncthreads();
        {
            constexpr int CH = BM * 4;
            #pragma unroll
            for (int i = 0; i < (CH + 511) / 512; ++i) {
                int idx = i * 512 + tid;
                if ((CH % 512) && idx >= CH) break;
                int row = idx >> 2, c = idx & 3;
                int4 a4 = *reinterpret_cast<const int4*>(&A[(size_t)(bm + row) * K + k0 + c * 8]);
                *reinterpret_cast<int4*>(reinterpret_cast<char*>(As)
                    + row * 64 + ((c ^ (row & 3)) << 4)) = a4;
            }
        }
        {
            #pragma unroll
            for (int i = 0; i < 2; ++i) {
                int idx = i * 512 + tid;
                int row = idx >> 2, c = idx & 3;
                int4 w4 = *reinterpret_cast<const int4*>(&W[(size_t)row * K + k0 + c * 8]);
                *reinterpret_cast<int4*>(reinterpret_cast<char*>(Bs)
                    + row * 64 + ((c ^ (row & 3)) << 4)) = w4;
            }
        }
        __syncthreads();
        bf16x8 af[MI], bfr[NI];
        #pragma unroll
        for (int i = 0; i < MI; ++i) {
            int r = wr * (BM / 2) + i * 16 + l15;
            af[i] = *reinterpret_cast<const bf16x8*>(
                reinterpret_cast<const char*>(As) + r * 64 + ((l4 ^ (r & 3)) << 4));
        }
        #pragma unroll
        for (int j = 0; j < NI; ++j) {
            int r = wc * 64 + j * 16 + l15;
            bfr[j] = *reinterpret_cast<const bf16x8*>(
                reinterpret_cast<const char*>(Bs) + r * 64 + ((l4 ^ (r & 3)) << 4));
        }
        #pragma unroll
        for (int i = 0; i < MI; ++i)
            #pragma unroll
            for (int j = 0; j < NI; ++j)
                acc[i][j] = __builtin_amdgcn_mfma_f32_16x16x32_bf16(
                    af[i], bfr[j], acc[i][j], 0, 0, 0);
    }

    const bool hi = DUAL && (bm >= (M >> 1));
    const int bmL = hi ? bm - (M >> 1) : bm;
    float* outp = (DUAL && hi) ? out1 : out0;

    #pragma unroll
    for (int i = 0; i < MI; ++i) {
        #pragma unroll
        for (int v = 0; v < 4; ++v) {
            int rloc = wr * (BM / 2) + i * 16 + l4 * 4 + v;
            size_t rrow = (size_t)(bmL + rloc) * 256;
            float s = 0.f, q = 0.f;
            #pragma unroll
            for (int j = 0; j < NI; ++j) {
                int col = wc * 64 + j * 16 + l15;
                float x = acc[i][j][v] + bias[col] + res[rrow + col];
                acc[i][j][v] = x;
                s += x; q += x * x;
            }
            #pragma unroll
            for (int msk = 1; msk < 16; msk <<= 1) {
                s += __shfl_xor(s, msk, 64);
                q += __shfl_xor(q, msk, 64);
            }
            if (l15 == 0) { redS[rloc][wc] = s; redQ[rloc][wc] = q; }
        }
    }
    __syncthreads();
    #pragma unroll
    for (int i = 0; i < MI; ++i) {
        #pragma unroll
        for (int v = 0; v < 4; ++v) {
            int rloc = wr * (BM / 2) + i * 16 + l4 * 4 + v;
            float S = redS[rloc][0] + redS[rloc][1] + redS[rloc][2] + redS[rloc][3];
            float Qs = redQ[rloc][0] + redQ[rloc][1] + redQ[rloc][2] + redQ[rloc][3];
            float mean = S * (1.f / 256.f);
            float var = Qs * (1.f / 256.f) - mean * mean;
            float rinv = rsqrtf(var + EPSf);
            size_t rrow = (size_t)(bmL + rloc) * 256;
            #pragma unroll
            for (int j = 0; j < NI; ++j) {
                int col = wc * 64 + j * 16 + l15;
                outp[rrow + col] = (acc[i][j][v] - mean) * rinv * lnw[col] + lnb[col];
            }
        }
    }
}

// ---------------------------------------------------------------------------
// oa GEMM (A = t + qpos, fp32; W = [off|attn]; N=256) with fused MSDA prep.
// ---------------------------------------------------------------------------
__global__ __launch_bounds__(512) void gemm_prep_kernel(
    const float* __restrict__ A, const float* __restrict__ A2,
    const unsigned short* __restrict__ W, const float* __restrict__ bias,
    const float* __restrict__ refv, const float* __restrict__ refa,
    float* __restrict__ vloc, float* __restrict__ vattn,
    float* __restrict__ aloc, float* __restrict__ aattn)
{
    constexpr int BM = 64, MI = 2, NI = 4;
    const int K = 256;
    __shared__ unsigned short As[BM * 32];
    __shared__ unsigned short Bs[256 * 32];
    const int tid = threadIdx.x, wid = tid >> 6, lane = tid & 63;
    const int wr = wid >> 2, wc = wid & 3;
    const int bm = blockIdx.x * BM;
    const int l15 = lane & 15, l4 = lane >> 4;
    f32x4 acc[MI][NI] = {};

    for (int k0 = 0; k0 < K; k0 += 32) {
        __syncthreads();
        {
            int idx = tid;
            int row = idx >> 3, c4 = idx & 7;
            size_t g = (size_t)(bm + row) * K + k0 + c4 * 4;
            float4 a4 = *reinterpret_cast<const float4*>(&A[g]);
            float4 b4 = *reinterpret_cast<const float4*>(&A2[g]);
            a4.x += b4.x; a4.y += b4.y; a4.z += b4.z; a4.w += b4.w;
            ushort4 u;
            u.x = rne_bf16(a4.x); u.y = rne_bf16(a4.y);
            u.z = rne_bf16(a4.z); u.w = rne_bf16(a4.w);
            *reinterpret_cast<ushort4*>(reinterpret_cast<char*>(As)
                + row * 64 + (((c4 >> 1) ^ (row & 3)) << 4) + (c4 & 1) * 8) = u;
        }
        {
            #pragma unroll
            for (int i = 0; i < 2; ++i) {
                int idx = i * 512 + tid;
                int row = idx >> 2, c = idx & 3;
                int4 w4 = *reinterpret_cast<const int4*>(&W[(size_t)row * K + k0 + c * 8]);
                *reinterpret_cast<int4*>(reinterpret_cast<char*>(Bs)
                    + row * 64 + ((c ^ (row & 3)) << 4)) = w4;
            }
        }
        __syncthreads();
        bf16x8 af[MI], bfr[NI];
        #pragma unroll
        for (int i = 0; i < MI; ++i) {
            int r = wr * 32 + i * 16 + l15;
            af[i] = *reinterpret_cast<const bf16x8*>(
                reinterpret_cast<const char*>(As) + r * 64 + ((l4 ^ (r & 3)) << 4));
        }
        #pragma unroll
        for (int j = 0; j < NI; ++j) {
            int r = wc * 64 + j * 16 + l15;
            bfr[j] = *reinterpret_cast<const bf16x8*>(
                reinterpret_cast<const char*>(Bs) + r * 64 + ((l4 ^ (r & 3)) << 4));
        }
        #pragma unroll
        for (int i = 0; i < MI; ++i)
            #pragma unroll
            for (int j = 0; j < NI; ++j)
                acc[i][j] = __builtin_amdgcn_mfma_f32_16x16x32_bf16(
                    af[i], bfr[j], acc[i][j], 0, 0, 0);
    }

    const float invT[4] = {1.f/8192.f, 1.f/4096.f, 1.f/2048.f, 1.f/1024.f};
    const int l = (l15 >> 2) & 3;
    if (wc < 2) {
        #pragma unroll
        for (int i = 0; i < MI; ++i) {
            #pragma unroll
            for (int v = 0; v < 4; ++v) {
                int tok = bm + wr * 32 + i * 16 + l4 * 4 + v;
                float rv = refv[(size_t)tok * 4 + l];
                float ra = refa[(size_t)tok * 4 + l];
                #pragma unroll
                for (int j = 0; j < NI; ++j) {
                    int col = wc * 64 + j * 16 + l15;
                    float off = (acc[i][j][v] + bias[col]) * invT[l];
                    vloc[(size_t)tok * 128 + col] = rv + off;
                    aloc[(size_t)tok * 128 + col] = ra + off;
                }
            }
        }
    } else {
        #pragma unroll
        for (int i = 0; i < MI; ++i) {
            #pragma unroll
            for (int v = 0; v < 4; ++v) {
                int tok = bm + wr * 32 + i * 16 + l4 * 4 + v;
                #pragma unroll
                for (int j = 0; j < NI; ++j) {
                    int col = wc * 64 + j * 16 + l15;
                    float lg = acc[i][j][v] + bias[col];
                    float m = lg;
                    #pragma unroll
                    for (int msk = 1; msk < 16; msk <<= 1)
                        m = fmaxf(m, __shfl_xor(m, msk, 64));
                    float e = __expf(lg - m);
                    float s = e;
                    #pragma unroll
                    for (int msk = 1; msk < 16; msk <<= 1)
                        s += __shfl_xor(s, msk, 64);
                    float at = e / s;
                    int c = col - 128;
                    vattn[(size_t)tok * 128 + c] = at;
                    aattn[(size_t)tok * 128 + c] = at;
                }
            }
        }
    }
}

// ---------------------------------------------------------------------------
// Flash self-attention (bf16 MFMA). Block = (b, h, 128-query tile).
// ---------------------------------------------------------------------------
__global__ __launch_bounds__(256) void sa_flash_kernel(
    const unsigned short* __restrict__ qkh, const unsigned short* __restrict__ vh,
    unsigned short* __restrict__ o)
{
    const int qt = blockIdx.x & 3;
    const int h  = (blockIdx.x >> 2) & 7;
    const int b  = blockIdx.x >> 5;
    const int tid = threadIdx.x;
    const int wid = tid >> 6;
    const int lane = tid & 63;
    const int l15 = lane & 15, l4 = lane >> 4;

    __shared__ unsigned short Ks[64 * 32];
    __shared__ unsigned short Vt[32 * 64];
    __shared__ unsigned short Ps[4][32 * 64];

    const int qbase = qt * 128 + wid * 32;
    bf16x8 qf[2];
    #pragma unroll
    for (int i = 0; i < 2; ++i) {
        int row = b * 512 + qbase + i * 16 + l15;
        qf[i] = *reinterpret_cast<const bf16x8*>(&qkh[(size_t)row * 512 + h * 32 + l4 * 8]);
    }

    f32x4 oacc[2][2] = {};
    float m_r[8], l_r[8];
    #pragma unroll
    for (int i = 0; i < 8; ++i) { m_r[i] = -1e30f; l_r[i] = 0.f; }

    for (int kt = 0; kt < 8; ++kt) {
        __syncthreads();
        {
            int row = tid >> 2, c = tid & 3;
            int4 k4 = *reinterpret_cast<const int4*>(
                &qkh[(size_t)(b * 512 + kt * 64 + row) * 512 + 256 + h * 32 + c * 8]);
            *reinterpret_cast<int4*>(reinterpret_cast<char*>(Ks)
                + row * 64 + ((c ^ (row & 3)) << 4)) = k4;
        }
        {
            int k = tid >> 2, dh0 = (tid & 3) * 8;
            const unsigned short* vp = &vh[(size_t)(b * 512 + kt * 64 + k) * 256 + h * 32 + dh0];
            ushort4 v0 = *reinterpret_cast<const ushort4*>(vp);
            ushort4 v1 = *reinterpret_cast<const ushort4*>(vp + 4);
            unsigned short vv[8] = {v0.x, v0.y, v0.z, v0.w, v1.x, v1.y, v1.z, v1.w};
            int kc = k >> 3, kb = (k & 7) * 2;
            #pragma unroll
            for (int j = 0; j < 8; ++j) {
                int dh = dh0 + j;
                *reinterpret_cast<unsigned short*>(reinterpret_cast<char*>(Vt)
                    + dh * 128 + ((kc ^ (dh & 7)) << 4) + kb) = vv[j];
            }
        }
        __syncthreads();

        bf16x8 kf[4];
        #pragma unroll
        for (int j = 0; j < 4; ++j) {
            int r = j * 16 + l15;
            kf[j] = *reinterpret_cast<const bf16x8*>(
                reinterpret_cast<const char*>(Ks) + r * 64 + ((l4 ^ (r & 3)) << 4));
        }
        f32x4 s[2][4];
        #pragma unroll
        for (int i = 0; i < 2; ++i)
            #pragma unroll
            for (int j = 0; j < 4; ++j) {
                f32x4 z = {0.f, 0.f, 0.f, 0.f};
                s[i][j] = __builtin_amdgcn_mfma_f32_16x16x32_bf16(qf[i], kf[j], z, 0, 0, 0);
            }

        #pragma unroll
        for (int i = 0; i < 2; ++i) {
            #pragma unroll
            for (int reg = 0; reg < 4; ++reg) {
                float v0 = s[i][0][reg] * SCALEf;
                float v1 = s[i][1][reg] * SCALEf;
                float v2 = s[i][2][reg] * SCALEf;
                float v3 = s[i][3][reg] * SCALEf;
                float mx = fmaxf(fmaxf(v0, v1), fmaxf(v2, v3));
                #pragma unroll
                for (int d = 1; d < 16; d <<= 1) mx = fmaxf(mx, __shfl_xor(mx, d, 64));
                int idx = i * 4 + reg;
                float mnew = fmaxf(m_r[idx], mx);
                float alpha = __expf(m_r[idx] - mnew);
                float p0 = __expf(v0 - mnew), p1 = __expf(v1 - mnew);
                float p2 = __expf(v2 - mnew), p3 = __expf(v3 - mnew);
                float rs = (p0 + p1) + (p2 + p3);
                #pragma unroll
                for (int d = 1; d < 16; d <<= 1) rs += __shfl_xor(rs, d, 64);
                l_r[idx] = l_r[idx] * alpha + rs;
                m_r[idx] = mnew;
                oacc[i][0][reg] *= alpha;
                oacc[i][1][reg] *= alpha;
                int row = i * 16 + l4 * 4 + reg;
                char* pbase = reinterpret_cast<char*>(Ps[wid]) + row * 128 + (l15 & 7) * 2;
                int ch = l15 >> 3;
                unsigned short pb[4] = {rne_bf16(p0), rne_bf16(p1), rne_bf16(p2), rne_bf16(p3)};
                #pragma unroll
                for (int j = 0; j < 4; ++j)
                    *reinterpret_cast<unsigned short*>(
                        pbase + (((j * 2 + ch) ^ (row & 7)) << 4)) = pb[j];
            }
        }
        asm volatile("s_waitcnt lgkmcnt(0)" ::: "memory");
        __builtin_amdgcn_sched_barrier(0);

        #pragma unroll
        for (int ks = 0; ks < 2; ++ks) {
            bf16x8 vf[2], pf[2];
            #pragma unroll
            for (int jd = 0; jd < 2; ++jd) {
                int r = jd * 16 + l15;
                vf[jd] = *reinterpret_cast<const bf16x8*>(
                    reinterpret_cast<const char*>(Vt) + r * 128 + (((ks * 4 + l4) ^ (r & 7)) << 4));
            }
            #pragma unroll
            for (int i = 0; i < 2; ++i) {
                int r = i * 16 + l15;
                pf[i] = *reinterpret_cast<const bf16x8*>(
                    reinterpret_cast<const char*>(Ps[wid]) + r * 128 + (((ks * 4 + l4) ^ (r & 7)) << 4));
            }
            #pragma unroll
            for (int i = 0; i < 2; ++i)
                #pragma unroll
                for (int jd = 0; jd < 2; ++jd)
                    oacc[i][jd] = __builtin_amdgcn_mfma_f32_16x16x32_bf16(
                        pf[i], vf[jd], oacc[i][jd], 0, 0, 0);
        }
    }

    #pragma unroll
    for (int i = 0; i < 2; ++i)
        #pragma unroll
        for (int reg = 0; reg < 4; ++reg) {
            int idx = i * 4 + reg;
            float inv = 1.f / l_r[idx];
            int qrow = b * 512 + qbase + i * 16 + l4 * 4 + reg;
            #pragma unroll
            for (int jd = 0; jd < 2; ++jd)
                o[(size_t)qrow * 256 + h * 32 + jd * 16 + l15] =
                    rne_bf16(oacc[i][jd][reg] * inv);
        }
}

// ---------------------------------------------------------------------------
// cat = LN(concat(tv,ta)) over 512 -> bf16 out. One block (256 thr) per token.
// ---------------------------------------------------------------------------
__global__ __launch_bounds__(256) void cat_ln_kernel(
    const float* __restrict__ tv, const float* __restrict__ ta,
    const float* __restrict__ w, const float* __restrict__ beta,
    unsigned short* __restrict__ out)
{
    const int tok = blockIdx.x;
    const int t = threadIdx.x;
    const float x0 = tv[(size_t)tok * 256 + t];
    const float x1 = ta[(size_t)tok * 256 + t];
    __shared__ float red[8];
    float s = x0 + x1;
    #pragma unroll
    for (int k = 32; k > 0; k >>= 1) s += __shfl_xor(s, k, 64);
    if ((t & 63) == 0) red[t >> 6] = s;
    __syncthreads();
    const float mean = (red[0] + red[1] + red[2] + red[3]) * (1.f / 512.f);
    const float d0 = x0 - mean, d1 = x1 - mean;
    float v = d0 * d0 + d1 * d1;
    #pragma unroll
    for (int k = 32; k > 0; k >>= 1) v += __shfl_xor(v, k, 64);
    if ((t & 63) == 0) red[4 + (t >> 6)] = v;
    __syncthreads();
    const float var = (red[4] + red[5] + red[6] + red[7]) * (1.f / 512.f);
    const float r = 1.f / sqrtf(var + EPSf);
    out[(size_t)tok * 512 + t]       = rne_bf16(d0 * r * w[t] + beta[t]);
    out[(size_t)tok * 512 + 256 + t] = rne_bf16(d1 * r * w[256 + t] + beta[256 + t]);
}

// ---------------------------------------------------------------------------
extern "C" void kernel_launch(void* const* d_in, const int* in_sizes, int n_in,
                              void* d_out, int out_size, void* d_ws, size_t ws_size,
                              hipStream_t stream)
{
    (void)in_sizes; (void)n_in; (void)out_size; (void)ws_size;
    const float* tgt       = (const float*)d_in[0];
    const float* query_pos = (const float*)d_in[1];
    const float* ref_v     = (const float*)d_in[2];
    const float* ref_a     = (const float*)d_in[3];
    const float* video_src = (const float*)d_in[5];
    const float* audio_src = (const float*)d_in[9];
    const float* sa_in_w   = (const float*)d_in[13];
    const float* sa_in_b   = (const float*)d_in[14];
    const float* sa_out_w  = (const float*)d_in[15];
    const float* sa_out_b  = (const float*)d_in[16];
    const float* ca_off_w  = (const float*)d_in[17];
    const float* ca_off_b  = (const float*)d_in[18];
    const float* ca_attn_w = (const float*)d_in[19];
    const float* ca_attn_b = (const float*)d_in[20];
    const float* ca_val_w  = (const float*)d_in[21];
    const float* ca_val_b  = (const float*)d_in[22];
    const float* ca_out_w  = (const float*)d_in[23];
    const float* ca_out_b  = (const float*)d_in[24];
    const float* n1_w = (const float*)d_in[25];
    const float* n1_b = (const float*)d_in[26];
    const float* n2_w = (const float*)d_in[27];
    const float* n2_b = (const float*)d_in[28];
    const float* n3_w = (const float*)d_in[29];
    const float* n3_b = (const float*)d_in[30];
    const float* n4_w = (const float*)d_in[31];
    const float* n4_b = (const float*)d_in[32];
    const float* lin1_w = (const float*)d_in[33];
    const float* lin1_b = (const float*)d_in[34];
    const float* lin2_w = (const float*)d_in[35];
    const float* lin2_b = (const float*)d_in[36];
    const float* lin3_w = (const float*)d_in[37];
    const float* lin3_b = (const float*)d_in[38];

    // ---- output slices (out, tv, ta, vloc, vattn, aloc, aattn)
    float* out_main  = (float*)d_out;
    float* out_tv    = out_main + (size_t)TOK * 256;
    float* out_ta    = out_tv   + (size_t)TOK * 256;
    float* out_vloc  = out_ta   + (size_t)TOK * 256;
    float* out_vattn = out_vloc + (size_t)TOK * 128;
    float* out_aloc  = out_vattn+ (size_t)TOK * 128;
    float* out_aattn = out_aloc + (size_t)TOK * 128;

    // ---- workspace (bytes)
    char* base = (char*)d_ws;
    const size_t MB = 1024 * 1024;
    unsigned short* f_qkh = (unsigned short*)(base + 0);        // 8MB  [0,8)
    unsigned short* f_vh  = (unsigned short*)(base + 8*MB);     // 4MB  [8,12)
    unsigned short* f_o   = (unsigned short*)(base + 12*MB);    // 4MB  [12,16)
    unsigned short* f_samp= (unsigned short*)(base + 0);        // 8MB  [0,8)   (after attn)
    unsigned short* f_cat = (unsigned short*)(base + 8*MB);     // 8MB  [8,16)  (after attn)
    unsigned short* f_ffh = (unsigned short*)(base + 16*MB);    // 16MB [16,32)
    float* f_t = (float*)(base + 32*MB);                        // 8MB
    float* f_x = (float*)(base + 40*MB);                        // 8MB
    unsigned short* f_agg = (unsigned short*)(base + 48*MB);    // 64MB  [8][16384][256] bf16
    float* f_sumw = (float*)(base + 112*MB);                    // 512KB [8][16384]
    unsigned short* wb = (unsigned short*)(base + 120*MB);      // 2.125MB bf16 weights
    unsigned short* w_sa_in  = wb;                    // 768*256
    unsigned short* w_sa_out = w_sa_in  + 768 * 256;
    unsigned short* w_oa     = w_sa_out + 256 * 256;  // off|attn
    unsigned short* w_val    = w_oa     + 256 * 256;
    unsigned short* w_caout  = w_val    + 256 * 256;
    unsigned short* w_lin3   = w_caout  + 256 * 256;
    unsigned short* w_lin1   = w_lin3   + 256 * 512;
    unsigned short* w_lin2   = w_lin1   + 1024 * 256;
    float* bias_oa = (float*)(w_lin2 + 256 * 1024);

    // 1. all weight conversions + bias concat (one launch)
    WcArgs wa;
    wa.src[0] = sa_in_w;  wa.src[1] = sa_out_w; wa.src[2] = ca_off_w;
    wa.src[3] = ca_attn_w;wa.src[4] = ca_val_w; wa.src[5] = ca_out_w;
    wa.src[6] = lin3_w;   wa.src[7] = lin1_w;   wa.src[8] = lin2_w;
    hipLaunchKernelGGL(wconv_kernel, dim3(1089), dim3(256), 0, stream,
                       wa, wb, ca_off_b, ca_attn_b, bias_oa);

    // 2. qk = (tgt+qpos) @ sa_in[0:512]^T -> bf16
    hipLaunchKernelGGL((gemm_mfma_kernel<64,128,false,false,true,true,false>),
                       dim3(128, 4), dim3(512), 0, stream,
                       tgt, nullptr, query_pos, w_sa_in, sa_in_b, f_qkh,
                       TOK, 512, 256, 0);
    // 3. v = tgt @ sa_in[512:768]^T -> bf16
    hipLaunchKernelGGL((gemm_mfma_kernel<64,128,false,false,true,false,false>),
                       dim3(128, 2), dim3(512), 0, stream,
                       tgt, nullptr, nullptr, w_sa_in + (size_t)512 * 256,
                       sa_in_b + 512, f_vh, TOK, 256, 256, 0);
    // 4. flash attention
    hipLaunchKernelGGL(sa_flash_kernel, dim3(Bb * 32), dim3(256), 0, stream,
                       f_qkh, f_vh, f_o);
    // 5. t = LN(tgt + o @ sa_out^T, n2)   [fused]
    hipLaunchKernelGGL((gemm_ln_kernel<32,false>), dim3(256), dim3(512), 0, stream,
                       f_o, w_sa_out, sa_out_b, tgt, n2_w, n2_b,
                       f_t, nullptr, TOK, 256);
    // 6. oa GEMM + msda prep -> vloc/vattn/aloc/aattn  [fused]
    hipLaunchKernelGGL(gemm_prep_kernel, dim3(128), dim3(512), 0, stream,
                       f_t, query_pos, w_oa, bias_oa, ref_v, ref_a,
                       out_vloc, out_vattn, out_aloc, out_aattn);
    // 7. MSDA aggregation over raw fp32 src (projection commuted out)
    hipLaunchKernelGGL(msda_agg_kernel, dim3(2 * TOK), dim3(256), 0, stream,
                       video_src, audio_src,
                       out_vloc, out_vattn, out_aloc, out_aattn,
                       f_agg, f_sumw);
    // 8. block-diagonal projection: samp = agg @ Wv[h]^T + bv*sumw -> bf16
    hipLaunchKernelGGL(agg_proj_kernel, dim3(2 * TOK / 64, 8), dim3(256), 0, stream,
                       f_agg, f_sumw, w_val, ca_val_b, f_samp);
    // 9. tv/ta = LN(t + samp @ ca_out^T, n1)  [fused, dual]
    hipLaunchKernelGGL((gemm_ln_kernel<64,true>), dim3(256), dim3(512), 0, stream,
                       f_samp, w_caout, ca_out_b, f_t, n1_w, n1_b,
                       out_tv, out_ta, 2 * TOK, 256);
    // 10. cat = LN(concat(tv,ta), n4) -> bf16
    hipLaunchKernelGGL(cat_ln_kernel, dim3(TOK), dim3(256), 0, stream,
                       out_tv, out_ta, n4_w, n4_b, f_cat);
    // 11. x = relu(cat @ lin3^T + b) -> fp32
    hipLaunchKernelGGL((gemm_mfma_kernel<64,128,true,true,false,false,false>),
                       dim3(128, 2), dim3(512), 0, stream,
                       f_cat, nullptr, nullptr, w_lin3, lin3_b, f_x,
                       TOK, 256, 512, 0);
    // 12. ffh = relu(x @ lin1^T + b) -> bf16
    hipLaunchKernelGGL((gemm_mfma_kernel<128,256,true,false,true,false,false>),
                       dim3(64, 4), dim3(512), 0, stream,
                       f_x, nullptr, nullptr, w_lin1, lin1_b, f_ffh,
                       TOK, 1024, 256, 0);
    // 13. out = LN(x + ffh @ lin2^T, n3)  [fused]
    hipLaunchKernelGGL((gemm_ln_kernel<32,false>), dim3(256), dim3(512), 0, stream,
                       f_ffh, w_lin2, lin2_b, f_x, n3_w, n3_b,
                       out_main, nullptr, TOK, 1024);
}

// Round 11
// 399.605 us; speedup vs baseline: 1.1565x; 1.1565x over previous
//
#include <hip/hip_runtime.h>
#include <hip/hip_bf16.h>
#include <cstddef>

#define Dm   256
#define Hh   8
#define Bb   16
#define Qq   512
#define Ss   15360
#define TOK  (Bb*Qq)          // 8192
#define VROWS (Bb*Ss)         // 245760
#define EPSf 1e-5f
#define SCALEf 0.17677669529663687f

typedef __attribute__((ext_vector_type(8))) short bf16x8;
typedef __attribute__((ext_vector_type(4))) float f32x4;

__device__ __forceinline__ unsigned short rne_bf16(float f) {
    unsigned int u = __builtin_bit_cast(unsigned int, f);
    u += 0x7fffu + ((u >> 16) & 1u);
    return (unsigned short)(u >> 16);
}
__device__ __forceinline__ float bf2f(unsigned short u) {
    return __builtin_bit_cast(float, (unsigned int)u << 16);
}

// ---------------------------------------------------------------------------
// One-shot weight conversion: 9 fp32 weight mats -> contiguous bf16 region,
// + ca bias concat. Grid = 1089 blocks x 256 thr (1088*256 float4 = exact).
// ---------------------------------------------------------------------------
struct WcArgs { const float* src[9]; };

__global__ __launch_bounds__(256) void wconv_kernel(
    WcArgs a, unsigned short* __restrict__ dst,
    const float* __restrict__ offb, const float* __restrict__ attnb,
    float* __restrict__ bias_oa)
{
    if (blockIdx.x == 1088) {
        int t = threadIdx.x;
        bias_oa[t] = (t < 128) ? offb[t] : attnb[t - 128];
        return;
    }
    int g = blockIdx.x * 256 + threadIdx.x;   // float4 index
    const int pre[10] = {0, 49152, 65536, 73728, 81920, 98304, 114688, 147456, 212992, 278528};
    int seg = 0;
    #pragma unroll
    for (int s2 = 1; s2 < 9; ++s2) seg += (g >= pre[s2]);
    float4 f = reinterpret_cast<const float4*>(a.src[seg])[g - pre[seg]];
    ushort4 o;
    o.x = rne_bf16(f.x); o.y = rne_bf16(f.y);
    o.z = rne_bf16(f.z); o.w = rne_bf16(f.w);
    reinterpret_cast<ushort4*>(dst)[g] = o;
}

// ---------------------------------------------------------------------------
// Streaming val GEMM (v1 structure + 2-deep k-chunk prefetch):
//   C[2*VROWS][256](bf16) = concat(Av,Aa)[.,256](fp32) @ W[256][256]^T + bias.
// 1024 thr = 16 waves; full W staged in 128KB LDS once; each wave streams
// 16 rows x 256 cols; A per-lane from global with TWO k-chunks in flight.
// ---------------------------------------------------------------------------
__global__ __launch_bounds__(1024, 4) void val_stream_kernel(
    const float* __restrict__ Av, const float* __restrict__ Aa,
    const unsigned short* __restrict__ W, const float* __restrict__ bias,
    unsigned short* __restrict__ C)
{
    __shared__ unsigned short Ws[8 * 256 * 32];   // 128 KB: 8 k-chunks of [256][32]
    const int tid = threadIdx.x;
    #pragma unroll
    for (int i = 0; i < 8; ++i) {
        int g = i * 1024 + tid;          // int4 index, 8192 total
        int r = g >> 5, q = g & 31;
        int c = q >> 2, ck = q & 3;
        int slot = ck ^ (r & 3) ^ ((r >> 2) & 3);
        int4 w4 = reinterpret_cast<const int4*>(W)[g];
        *reinterpret_cast<int4*>(reinterpret_cast<char*>(Ws)
            + c * 16384 + r * 64 + (slot << 4)) = w4;
    }
    __syncthreads();

    const int wid = tid >> 6, lane = tid & 63;
    const int l15 = lane & 15, l4 = lane >> 4;
    size_t grow = (size_t)blockIdx.x * 256 + wid * 16;
    const float* A = Av;
    size_t arow = grow;
    if (grow >= (size_t)VROWS) { A = Aa; arow = grow - VROWS; }
    const float* aptr = A + (arow + l15) * 256 + l4 * 8;

    f32x4 acc[16] = {};
    // 2-deep prefetch: chunks kc and kc+1 live in registers
    float4 c0a = *reinterpret_cast<const float4*>(aptr);
    float4 c0b = *reinterpret_cast<const float4*>(aptr + 4);
    float4 c1a = *reinterpret_cast<const float4*>(aptr + 32);
    float4 c1b = *reinterpret_cast<const float4*>(aptr + 36);
    #pragma unroll
    for (int kc = 0; kc < 8; ++kc) {
        float4 n0, n1;
        if (kc < 6) {
            n0 = *reinterpret_cast<const float4*>(aptr + (kc + 2) * 32);
            n1 = *reinterpret_cast<const float4*>(aptr + (kc + 2) * 32 + 4);
        }
        bf16x8 af;
        af[0] = (short)rne_bf16(c0a.x); af[1] = (short)rne_bf16(c0a.y);
        af[2] = (short)rne_bf16(c0a.z); af[3] = (short)rne_bf16(c0a.w);
        af[4] = (short)rne_bf16(c0b.x); af[5] = (short)rne_bf16(c0b.y);
        af[6] = (short)rne_bf16(c0b.z); af[7] = (short)rne_bf16(c0b.w);
        const char* wbase = reinterpret_cast<const char*>(Ws) + kc * 16384;
        #pragma unroll
        for (int n = 0; n < 16; ++n) {
            int r = n * 16 + l15;
            int slot = l4 ^ (r & 3) ^ ((r >> 2) & 3);
            bf16x8 bf = *reinterpret_cast<const bf16x8*>(wbase + r * 64 + (slot << 4));
            acc[n] = __builtin_amdgcn_mfma_f32_16x16x32_bf16(af, bf, acc[n], 0, 0, 0);
        }
        c0a = c1a; c0b = c1b;
        if (kc < 6) { c1a = n0; c1b = n1; }
    }
    #pragma unroll
    for (int n = 0; n < 16; ++n) {
        int col = n * 16 + l15;
        float bv = bias[col];
        size_t r0 = grow + l4 * 4;
        #pragma unroll
        for (int v = 0; v < 4; ++v)
            C[(r0 + v) * 256 + col] = rne_bf16(acc[n][v] + bv);
    }
}

// ---------------------------------------------------------------------------
// Generic MFMA GEMM: C[M,N] = A[M,K] @ W[N,K](bf16)^T + bias, opt. ReLU.
// 512 thr = 8 waves (2x4), wave tile (BM/2)x(BN/4), 16x16x32 bf16, BK=32.
// ABF: A bf16; ADD: A += A2 (fp32); OBF: bf16 out; SPLITA: A/Ab at Msplit.
// ---------------------------------------------------------------------------
template<int BM, int BN, bool RELU, bool ABF, bool OBF, bool ADD, bool SPLITA>
__global__ __launch_bounds__(512) void gemm_mfma_kernel(
    const void* __restrict__ Ap, const void* __restrict__ Ap2,
    const float* __restrict__ A2,
    const unsigned short* __restrict__ W,
    const float* __restrict__ bias, void* __restrict__ Cp,
    int M, int N, int K, int Msplit)
{
    constexpr int MI = BM / 32;
    constexpr int NI = BN / 64;
    __shared__ unsigned short As[BM * 32];
    __shared__ unsigned short Bs[BN * 32];
    const int tid = threadIdx.x, wid = tid >> 6, lane = tid & 63;
    const int wr = wid >> 2, wc = wid & 3;
    const int bm = blockIdx.x * BM, bn = blockIdx.y * BN;
    const int l15 = lane & 15, l4 = lane >> 4;
    const void* Ause = Ap;
    int bmA = bm;
    if (SPLITA && bm >= Msplit) { Ause = Ap2; bmA = bm - Msplit; }
    f32x4 acc[MI][NI] = {};

    for (int k0 = 0; k0 < K; k0 += 32) {
        __syncthreads();
        if (ABF) {
            const unsigned short* A = (const unsigned short*)Ause;
            constexpr int CH = BM * 4;
            #pragma unroll
            for (int i = 0; i < (CH + 511) / 512; ++i) {
                int idx = i * 512 + tid;
                if ((CH % 512) && idx >= CH) break;
                int row = idx >> 2, c = idx & 3;
                int4 a4 = *reinterpret_cast<const int4*>(&A[(size_t)(bmA + row) * K + k0 + c * 8]);
                *reinterpret_cast<int4*>(reinterpret_cast<char*>(As)
                    + row * 64 + ((c ^ (row & 3)) << 4)) = a4;
            }
        } else {
            const float* A = (const float*)Ause;
            constexpr int CH = BM * 8;
            #pragma unroll
            for (int i = 0; i < CH / 512; ++i) {
                int idx = i * 512 + tid;
                int row = idx >> 3, c4 = idx & 7;
                size_t g = (size_t)(bmA + row) * K + k0 + c4 * 4;
                float4 a4 = *reinterpret_cast<const float4*>(&A[g]);
                if (ADD) {
                    float4 b4 = *reinterpret_cast<const float4*>(
                        &A2[(size_t)(bm + row) * K + k0 + c4 * 4]);
                    a4.x += b4.x; a4.y += b4.y; a4.z += b4.z; a4.w += b4.w;
                }
                ushort4 u;
                u.x = rne_bf16(a4.x); u.y = rne_bf16(a4.y);
                u.z = rne_bf16(a4.z); u.w = rne_bf16(a4.w);
                *reinterpret_cast<ushort4*>(reinterpret_cast<char*>(As)
                    + row * 64 + (((c4 >> 1) ^ (row & 3)) << 4) + (c4 & 1) * 8) = u;
            }
        }
        {
            constexpr int CH = BN * 4;
            #pragma unroll
            for (int i = 0; i < CH / 512; ++i) {
                int idx = i * 512 + tid;
                int row = idx >> 2, c = idx & 3;
                int4 w4 = *reinterpret_cast<const int4*>(&W[(size_t)(bn + row) * K + k0 + c * 8]);
                *reinterpret_cast<int4*>(reinterpret_cast<char*>(Bs)
                    + row * 64 + ((c ^ (row & 3)) << 4)) = w4;
            }
        }
        __syncthreads();
        bf16x8 af[MI], bfr[NI];
        #pragma unroll
        for (int i = 0; i < MI; ++i) {
            int r = wr * (BM / 2) + i * 16 + l15;
            af[i] = *reinterpret_cast<const bf16x8*>(
                reinterpret_cast<const char*>(As) + r * 64 + ((l4 ^ (r & 3)) << 4));
        }
        #pragma unroll
        for (int j = 0; j < NI; ++j) {
            int r = wc * (BN / 4) + j * 16 + l15;
            bfr[j] = *reinterpret_cast<const bf16x8*>(
                reinterpret_cast<const char*>(Bs) + r * 64 + ((l4 ^ (r & 3)) << 4));
        }
        #pragma unroll
        for (int i = 0; i < MI; ++i)
            #pragma unroll
            for (int j = 0; j < NI; ++j)
                acc[i][j] = __builtin_amdgcn_mfma_f32_16x16x32_bf16(
                    af[i], bfr[j], acc[i][j], 0, 0, 0);
    }
    #pragma unroll
    for (int j = 0; j < NI; ++j) {
        int col = bn + wc * (BN / 4) + j * 16 + l15;
        float bv = bias[col];
        #pragma unroll
        for (int i = 0; i < MI; ++i) {
            int row0 = bm + wr * (BM / 2) + i * 16 + l4 * 4;
            #pragma unroll
            for (int v = 0; v < 4; ++v) {
                float val = acc[i][j][v] + bv;
                if (RELU) val = fmaxf(val, 0.f);
                if (OBF)
                    ((unsigned short*)Cp)[(size_t)(row0 + v) * N + col] = rne_bf16(val);
                else
                    ((float*)Cp)[(size_t)(row0 + v) * N + col] = val;
            }
        }
    }
}

// ---------------------------------------------------------------------------
// MFMA GEMM (bf16 A, N=256=BN) with fused residual-add + LayerNorm epilogue.
// out = LN(res + A@W^T + bias) * lnw + lnb   (fp32 out).
// DUAL: rows >= M/2 go to out1 with res/row rebased (video/audio batch).
// ---------------------------------------------------------------------------
template<int BM, bool DUAL>
__global__ __launch_bounds__(512) void gemm_ln_kernel(
    const unsigned short* __restrict__ A,
    const unsigned short* __restrict__ W,
    const float* __restrict__ bias,
    const float* __restrict__ res,
    const float* __restrict__ lnw, const float* __restrict__ lnb,
    float* __restrict__ out0, float* __restrict__ out1,
    int M, int K)
{
    constexpr int MI = BM / 32;
    constexpr int NI = 4;               // BN = 256
    __shared__ unsigned short As[BM * 32];
    __shared__ unsigned short Bs[256 * 32];
    __shared__ float redS[BM][4];
    __shared__ float redQ[BM][4];
    const int tid = threadIdx.x, wid = tid >> 6, lane = tid & 63;
    const int wr = wid >> 2, wc = wid & 3;
    const int bm = blockIdx.x * BM;
    const int l15 = lane & 15, l4 = lane >> 4;
    f32x4 acc[MI][NI] = {};

    for (int k0 = 0; k0 < K; k0 += 32) {
        __syncthreads();
        {
            constexpr int CH = BM * 4;
            #pragma unroll
            for (int i = 0; i < (CH + 511) / 512; ++i) {
                int idx = i * 512 + tid;
                if ((CH % 512) && idx >= CH) break;
                int row = idx >> 2, c = idx & 3;
                int4 a4 = *reinterpret_cast<const int4*>(&A[(size_t)(bm + row) * K + k0 + c * 8]);
                *reinterpret_cast<int4*>(reinterpret_cast<char*>(As)
                    + row * 64 + ((c ^ (row & 3)) << 4)) = a4;
            }
        }
        {
            #pragma unroll
            for (int i = 0; i < 2; ++i) {
                int idx = i * 512 + tid;
                int row = idx >> 2, c = idx & 3;
                int4 w4 = *reinterpret_cast<const int4*>(&W[(size_t)row * K + k0 + c * 8]);
                *reinterpret_cast<int4*>(reinterpret_cast<char*>(Bs)
                    + row * 64 + ((c ^ (row & 3)) << 4)) = w4;
            }
        }
        __syncthreads();
        bf16x8 af[MI], bfr[NI];
        #pragma unroll
        for (int i = 0; i < MI; ++i) {
            int r = wr * (BM / 2) + i * 16 + l15;
            af[i] = *reinterpret_cast<const bf16x8*>(
                reinterpret_cast<const char*>(As) + r * 64 + ((l4 ^ (r & 3)) << 4));
        }
        #pragma unroll
        for (int j = 0; j < NI; ++j) {
            int r = wc * 64 + j * 16 + l15;
            bfr[j] = *reinterpret_cast<const bf16x8*>(
                reinterpret_cast<const char*>(Bs) + r * 64 + ((l4 ^ (r & 3)) << 4));
        }
        #pragma unroll
        for (int i = 0; i < MI; ++i)
            #pragma unroll
            for (int j = 0; j < NI; ++j)
                acc[i][j] = __builtin_amdgcn_mfma_f32_16x16x32_bf16(
                    af[i], bfr[j], acc[i][j], 0, 0, 0);
    }

    const bool hi = DUAL && (bm >= (M >> 1));
    const int bmL = hi ? bm - (M >> 1) : bm;
    float* outp = (DUAL && hi) ? out1 : out0;

    #pragma unroll
    for (int i = 0; i < MI; ++i) {
        #pragma unroll
        for (int v = 0; v < 4; ++v) {
            int rloc = wr * (BM / 2) + i * 16 + l4 * 4 + v;
            size_t rrow = (size_t)(bmL + rloc) * 256;
            float s = 0.f, q = 0.f;
            #pragma unroll
            for (int j = 0; j < NI; ++j) {
                int col = wc * 64 + j * 16 + l15;
                float x = acc[i][j][v] + bias[col] + res[rrow + col];
                acc[i][j][v] = x;
                s += x; q += x * x;
            }
            #pragma unroll
            for (int msk = 1; msk < 16; msk <<= 1) {
                s += __shfl_xor(s, msk, 64);
                q += __shfl_xor(q, msk, 64);
            }
            if (l15 == 0) { redS[rloc][wc] = s; redQ[rloc][wc] = q; }
        }
    }
    __syncthreads();
    #pragma unroll
    for (int i = 0; i < MI; ++i) {
        #pragma unroll
        for (int v = 0; v < 4; ++v) {
            int rloc = wr * (BM / 2) + i * 16 + l4 * 4 + v;
            float S = redS[rloc][0] + redS[rloc][1] + redS[rloc][2] + redS[rloc][3];
            float Qs = redQ[rloc][0] + redQ[rloc][1] + redQ[rloc][2] + redQ[rloc][3];
            float mean = S * (1.f / 256.f);
            float var = Qs * (1.f / 256.f) - mean * mean;
            float rinv = rsqrtf(var + EPSf);
            size_t rrow = (size_t)(bmL + rloc) * 256;
            #pragma unroll
            for (int j = 0; j < NI; ++j) {
                int col = wc * 64 + j * 16 + l15;
                outp[rrow + col] = (acc[i][j][v] - mean) * rinv * lnw[col] + lnb[col];
            }
        }
    }
}

// ---------------------------------------------------------------------------
// oa GEMM (A = t + qpos, fp32; W = [off|attn]; N=256) with fused MSDA prep.
// ---------------------------------------------------------------------------
__global__ __launch_bounds__(512) void gemm_prep_kernel(
    const float* __restrict__ A, const float* __restrict__ A2,
    const unsigned short* __restrict__ W, const float* __restrict__ bias,
    const float* __restrict__ refv, const float* __restrict__ refa,
    float* __restrict__ vloc, float* __restrict__ vattn,
    float* __restrict__ aloc, float* __restrict__ aattn)
{
    constexpr int BM = 64, MI = 2, NI = 4;
    const int K = 256;
    __shared__ unsigned short As[BM * 32];
    __shared__ unsigned short Bs[256 * 32];
    const int tid = threadIdx.x, wid = tid >> 6, lane = tid & 63;
    const int wr = wid >> 2, wc = wid & 3;
    const int bm = blockIdx.x * BM;
    const int l15 = lane & 15, l4 = lane >> 4;
    f32x4 acc[MI][NI] = {};

    for (int k0 = 0; k0 < K; k0 += 32) {
        __syncthreads();
        {
            int idx = tid;
            int row = idx >> 3, c4 = idx & 7;
            size_t g = (size_t)(bm + row) * K + k0 + c4 * 4;
            float4 a4 = *reinterpret_cast<const float4*>(&A[g]);
            float4 b4 = *reinterpret_cast<const float4*>(&A2[g]);
            a4.x += b4.x; a4.y += b4.y; a4.z += b4.z; a4.w += b4.w;
            ushort4 u;
            u.x = rne_bf16(a4.x); u.y = rne_bf16(a4.y);
            u.z = rne_bf16(a4.z); u.w = rne_bf16(a4.w);
            *reinterpret_cast<ushort4*>(reinterpret_cast<char*>(As)
                + row * 64 + (((c4 >> 1) ^ (row & 3)) << 4) + (c4 & 1) * 8) = u;
        }
        {
            #pragma unroll
            for (int i = 0; i < 2; ++i) {
                int idx = i * 512 + tid;
                int row = idx >> 2, c = idx & 3;
                int4 w4 = *reinterpret_cast<const int4*>(&W[(size_t)row * K + k0 + c * 8]);
                *reinterpret_cast<int4*>(reinterpret_cast<char*>(Bs)
                    + row * 64 + ((c ^ (row & 3)) << 4)) = w4;
            }
        }
        __syncthreads();
        bf16x8 af[MI], bfr[NI];
        #pragma unroll
        for (int i = 0; i < MI; ++i) {
            int r = wr * 32 + i * 16 + l15;
            af[i] = *reinterpret_cast<const bf16x8*>(
                reinterpret_cast<const char*>(As) + r * 64 + ((l4 ^ (r & 3)) << 4));
        }
        #pragma unroll
        for (int j = 0; j < NI; ++j) {
            int r = wc * 64 + j * 16 + l15;
            bfr[j] = *reinterpret_cast<const bf16x8*>(
                reinterpret_cast<const char*>(Bs) + r * 64 + ((l4 ^ (r & 3)) << 4));
        }
        #pragma unroll
        for (int i = 0; i < MI; ++i)
            #pragma unroll
            for (int j = 0; j < NI; ++j)
                acc[i][j] = __builtin_amdgcn_mfma_f32_16x16x32_bf16(
                    af[i], bfr[j], acc[i][j], 0, 0, 0);
    }

    const float invT[4] = {1.f/8192.f, 1.f/4096.f, 1.f/2048.f, 1.f/1024.f};
    const int l = (l15 >> 2) & 3;
    if (wc < 2) {
        #pragma unroll
        for (int i = 0; i < MI; ++i) {
            #pragma unroll
            for (int v = 0; v < 4; ++v) {
                int tok = bm + wr * 32 + i * 16 + l4 * 4 + v;
                float rv = refv[(size_t)tok * 4 + l];
                float ra = refa[(size_t)tok * 4 + l];
                #pragma unroll
                for (int j = 0; j < NI; ++j) {
                    int col = wc * 64 + j * 16 + l15;
                    float off = (acc[i][j][v] + bias[col]) * invT[l];
                    vloc[(size_t)tok * 128 + col] = rv + off;
                    aloc[(size_t)tok * 128 + col] = ra + off;
                }
            }
        }
    } else {
        #pragma unroll
        for (int i = 0; i < MI; ++i) {
            #pragma unroll
            for (int v = 0; v < 4; ++v) {
                int tok = bm + wr * 32 + i * 16 + l4 * 4 + v;
                #pragma unroll
                for (int j = 0; j < NI; ++j) {
                    int col = wc * 64 + j * 16 + l15;
                    float lg = acc[i][j][v] + bias[col];
                    float m = lg;
                    #pragma unroll
                    for (int msk = 1; msk < 16; msk <<= 1)
                        m = fmaxf(m, __shfl_xor(m, msk, 64));
                    float e = __expf(lg - m);
                    float s = e;
                    #pragma unroll
                    for (int msk = 1; msk < 16; msk <<= 1)
                        s += __shfl_xor(s, msk, 64);
                    float at = e / s;
                    int c = col - 128;
                    vattn[(size_t)tok * 128 + c] = at;
                    aattn[(size_t)tok * 128 + c] = at;
                }
            }
        }
    }
}

// ---------------------------------------------------------------------------
// Flash self-attention (bf16 MFMA). Block = (b, h, 128-query tile).
// ---------------------------------------------------------------------------
__global__ __launch_bounds__(256) void sa_flash_kernel(
    const unsigned short* __restrict__ qkh, const unsigned short* __restrict__ vh,
    unsigned short* __restrict__ o)
{
    const int qt = blockIdx.x & 3;
    const int h  = (blockIdx.x >> 2) & 7;
    const int b  = blockIdx.x >> 5;
    const int tid = threadIdx.x;
    const int wid = tid >> 6;
    const int lane = tid & 63;
    const int l15 = lane & 15, l4 = lane >> 4;

    __shared__ unsigned short Ks[64 * 32];
    __shared__ unsigned short Vt[32 * 64];
    __shared__ unsigned short Ps[4][32 * 64];

    const int qbase = qt * 128 + wid * 32;
    bf16x8 qf[2];
    #pragma unroll
    for (int i = 0; i < 2; ++i) {
        int row = b * 512 + qbase + i * 16 + l15;
        qf[i] = *reinterpret_cast<const bf16x8*>(&qkh[(size_t)row * 512 + h * 32 + l4 * 8]);
    }

    f32x4 oacc[2][2] = {};
    float m_r[8], l_r[8];
    #pragma unroll
    for (int i = 0; i < 8; ++i) { m_r[i] = -1e30f; l_r[i] = 0.f; }

    for (int kt = 0; kt < 8; ++kt) {
        __syncthreads();
        {
            int row = tid >> 2, c = tid & 3;
            int4 k4 = *reinterpret_cast<const int4*>(
                &qkh[(size_t)(b * 512 + kt * 64 + row) * 512 + 256 + h * 32 + c * 8]);
            *reinterpret_cast<int4*>(reinterpret_cast<char*>(Ks)
                + row * 64 + ((c ^ (row & 3)) << 4)) = k4;
        }
        {
            int k = tid >> 2, dh0 = (tid & 3) * 8;
            const unsigned short* vp = &vh[(size_t)(b * 512 + kt * 64 + k) * 256 + h * 32 + dh0];
            ushort4 v0 = *reinterpret_cast<const ushort4*>(vp);
            ushort4 v1 = *reinterpret_cast<const ushort4*>(vp + 4);
            unsigned short vv[8] = {v0.x, v0.y, v0.z, v0.w, v1.x, v1.y, v1.z, v1.w};
            int kc = k >> 3, kb = (k & 7) * 2;
            #pragma unroll
            for (int j = 0; j < 8; ++j) {
                int dh = dh0 + j;
                *reinterpret_cast<unsigned short*>(reinterpret_cast<char*>(Vt)
                    + dh * 128 + ((kc ^ (dh & 7)) << 4) + kb) = vv[j];
            }
        }
        __syncthreads();

        bf16x8 kf[4];
        #pragma unroll
        for (int j = 0; j < 4; ++j) {
            int r = j * 16 + l15;
            kf[j] = *reinterpret_cast<const bf16x8*>(
                reinterpret_cast<const char*>(Ks) + r * 64 + ((l4 ^ (r & 3)) << 4));
        }
        f32x4 s[2][4];
        #pragma unroll
        for (int i = 0; i < 2; ++i)
            #pragma unroll
            for (int j = 0; j < 4; ++j) {
                f32x4 z = {0.f, 0.f, 0.f, 0.f};
                s[i][j] = __builtin_amdgcn_mfma_f32_16x16x32_bf16(qf[i], kf[j], z, 0, 0, 0);
            }

        #pragma unroll
        for (int i = 0; i < 2; ++i) {
            #pragma unroll
            for (int reg = 0; reg < 4; ++reg) {
                float v0 = s[i][0][reg] * SCALEf;
                float v1 = s[i][1][reg] * SCALEf;
                float v2 = s[i][2][reg] * SCALEf;
                float v3 = s[i][3][reg] * SCALEf;
                float mx = fmaxf(fmaxf(v0, v1), fmaxf(v2, v3));
                #pragma unroll
                for (int d = 1; d < 16; d <<= 1) mx = fmaxf(mx, __shfl_xor(mx, d, 64));
                int idx = i * 4 + reg;
                float mnew = fmaxf(m_r[idx], mx);
                float alpha = __expf(m_r[idx] - mnew);
                float p0 = __expf(v0 - mnew), p1 = __expf(v1 - mnew);
                float p2 = __expf(v2 - mnew), p3 = __expf(v3 - mnew);
                float rs = (p0 + p1) + (p2 + p3);
                #pragma unroll
                for (int d = 1; d < 16; d <<= 1) rs += __shfl_xor(rs, d, 64);
                l_r[idx] = l_r[idx] * alpha + rs;
                m_r[idx] = mnew;
                oacc[i][0][reg] *= alpha;
                oacc[i][1][reg] *= alpha;
                int row = i * 16 + l4 * 4 + reg;
                char* pbase = reinterpret_cast<char*>(Ps[wid]) + row * 128 + (l15 & 7) * 2;
                int ch = l15 >> 3;
                unsigned short pb[4] = {rne_bf16(p0), rne_bf16(p1), rne_bf16(p2), rne_bf16(p3)};
                #pragma unroll
                for (int j = 0; j < 4; ++j)
                    *reinterpret_cast<unsigned short*>(
                        pbase + (((j * 2 + ch) ^ (row & 7)) << 4)) = pb[j];
            }
        }
        asm volatile("s_waitcnt lgkmcnt(0)" ::: "memory");
        __builtin_amdgcn_sched_barrier(0);

        #pragma unroll
        for (int ks = 0; ks < 2; ++ks) {
            bf16x8 vf[2], pf[2];
            #pragma unroll
            for (int jd = 0; jd < 2; ++jd) {
                int r = jd * 16 + l15;
                vf[jd] = *reinterpret_cast<const bf16x8*>(
                    reinterpret_cast<const char*>(Vt) + r * 128 + (((ks * 4 + l4) ^ (r & 7)) << 4));
            }
            #pragma unroll
            for (int i = 0; i < 2; ++i) {
                int r = i * 16 + l15;
                pf[i] = *reinterpret_cast<const bf16x8*>(
                    reinterpret_cast<const char*>(Ps[wid]) + r * 128 + (((ks * 4 + l4) ^ (r & 7)) << 4));
            }
            #pragma unroll
            for (int i = 0; i < 2; ++i)
                #pragma unroll
                for (int jd = 0; jd < 2; ++jd)
                    oacc[i][jd] = __builtin_amdgcn_mfma_f32_16x16x32_bf16(
                        pf[i], vf[jd], oacc[i][jd], 0, 0, 0);
        }
    }

    #pragma unroll
    for (int i = 0; i < 2; ++i)
        #pragma unroll
        for (int reg = 0; reg < 4; ++reg) {
            int idx = i * 4 + reg;
            float inv = 1.f / l_r[idx];
            int qrow = b * 512 + qbase + i * 16 + l4 * 4 + reg;
            #pragma unroll
            for (int jd = 0; jd < 2; ++jd)
                o[(size_t)qrow * 256 + h * 32 + jd * 16 + l15] =
                    rne_bf16(oacc[i][jd][reg] * inv);
        }
}

// ---------------------------------------------------------------------------
// cat = LN(concat(tv,ta)) over 512 -> bf16 out. One block (256 thr) per token.
// ---------------------------------------------------------------------------
__global__ __launch_bounds__(256) void cat_ln_kernel(
    const float* __restrict__ tv, const float* __restrict__ ta,
    const float* __restrict__ w, const float* __restrict__ beta,
    unsigned short* __restrict__ out)
{
    const int tok = blockIdx.x;
    const int t = threadIdx.x;
    const float x0 = tv[(size_t)tok * 256 + t];
    const float x1 = ta[(size_t)tok * 256 + t];
    __shared__ float red[8];
    float s = x0 + x1;
    #pragma unroll
    for (int k = 32; k > 0; k >>= 1) s += __shfl_xor(s, k, 64);
    if ((t & 63) == 0) red[t >> 6] = s;
    __syncthreads();
    const float mean = (red[0] + red[1] + red[2] + red[3]) * (1.f / 512.f);
    const float d0 = x0 - mean, d1 = x1 - mean;
    float v = d0 * d0 + d1 * d1;
    #pragma unroll
    for (int k = 32; k > 0; k >>= 1) v += __shfl_xor(v, k, 64);
    if ((t & 63) == 0) red[4 + (t >> 6)] = v;
    __syncthreads();
    const float var = (red[4] + red[5] + red[6] + red[7]) * (1.f / 512.f);
    const float r = 1.f / sqrtf(var + EPSf);
    out[(size_t)tok * 512 + t]       = rne_bf16(d0 * r * w[t] + beta[t]);
    out[(size_t)tok * 512 + 256 + t] = rne_bf16(d1 * r * w[256 + t] + beta[256 + t]);
}

// ---------------------------------------------------------------------------
// Combined MSDA sampling for both modalities. Grid = 2*TOK/4 blocks.
// ---------------------------------------------------------------------------
__global__ __launch_bounds__(256) void msda_sample_kernel(
    const unsigned short* __restrict__ val,
    const float* __restrict__ vloc, const float* __restrict__ vattn,
    const float* __restrict__ aloc, const float* __restrict__ aattn,
    unsigned short* __restrict__ out)
{
    const int t = threadIdx.x;
    const int tq = t >> 6;
    const int h  = (t >> 3) & 7;
    const int d4 = t & 7;
    const int tok2 = blockIdx.x * 4 + tq;
    const int mod = tok2 >> 13;
    const int tok = tok2 & 8191;
    const int b = tok >> 9;
    const float* loc  = mod ? aloc  : vloc;
    const float* attn = mod ? aattn : vattn;
    const unsigned short* vbase = val + (size_t)mod * VROWS * 256
                                + (size_t)b * Ss * 256 + h * 32 + d4 * 4;
    const int Tt[4]   = {8192, 4096, 2048, 1024};
    const int LSIc[4] = {0, 8192, 12288, 14336};
    float4 acc = {0.f, 0.f, 0.f, 0.f};
    #pragma unroll
    for (int l = 0; l < 4; ++l) {
        const unsigned short* vl = vbase + (size_t)LSIc[l] * 256;
        const int T = Tt[l];
        #pragma unroll
        for (int p = 0; p < 4; ++p) {
            const int e = (h * 4 + l) * 4 + p;
            const float lc = loc[(size_t)tok * 128 + e];
            const float at = attn[(size_t)tok * 128 + e];
            const float x = lc * (float)T - 0.5f;
            const float x0 = floorf(x);
            const float w = x - x0;
            const int i0 = (int)x0;
            const int i1 = i0 + 1;
            const float w0 = (i0 >= 0 && i0 < T) ? at * (1.f - w) : 0.f;
            const float w1 = (i1 >= 0 && i1 < T) ? at * w : 0.f;
            const int i0c = min(max(i0, 0), T - 1);
            const int i1c = min(max(i1, 0), T - 1);
            ushort4 g0 = *reinterpret_cast<const ushort4*>(&vl[(size_t)i0c * 256]);
            ushort4 g1 = *reinterpret_cast<const ushort4*>(&vl[(size_t)i1c * 256]);
            acc.x += w0 * bf2f(g0.x) + w1 * bf2f(g1.x);
            acc.y += w0 * bf2f(g0.y) + w1 * bf2f(g1.y);
            acc.z += w0 * bf2f(g0.z) + w1 * bf2f(g1.z);
            acc.w += w0 * bf2f(g0.w) + w1 * bf2f(g1.w);
        }
    }
    ushort4 ov;
    ov.x = rne_bf16(acc.x); ov.y = rne_bf16(acc.y);
    ov.z = rne_bf16(acc.z); ov.w = rne_bf16(acc.w);
    *reinterpret_cast<ushort4*>(&out[(size_t)tok2 * 256 + h * 32 + d4 * 4]) = ov;
}

// ---------------------------------------------------------------------------
extern "C" void kernel_launch(void* const* d_in, const int* in_sizes, int n_in,
                              void* d_out, int out_size, void* d_ws, size_t ws_size,
                              hipStream_t stream)
{
    (void)in_sizes; (void)n_in; (void)out_size; (void)ws_size;
    const float* tgt       = (const float*)d_in[0];
    const float* query_pos = (const float*)d_in[1];
    const float* ref_v     = (const float*)d_in[2];
    const float* ref_a     = (const float*)d_in[3];
    const float* video_src = (const float*)d_in[5];
    const float* audio_src = (const float*)d_in[9];
    const float* sa_in_w   = (const float*)d_in[13];
    const float* sa_in_b   = (const float*)d_in[14];
    const float* sa_out_w  = (const float*)d_in[15];
    const float* sa_out_b  = (const float*)d_in[16];
    const float* ca_off_w  = (const float*)d_in[17];
    const float* ca_off_b  = (const float*)d_in[18];
    const float* ca_attn_w = (const float*)d_in[19];
    const float* ca_attn_b = (const float*)d_in[20];
    const float* ca_val_w  = (const float*)d_in[21];
    const float* ca_val_b  = (const float*)d_in[22];
    const float* ca_out_w  = (const float*)d_in[23];
    const float* ca_out_b  = (const float*)d_in[24];
    const float* n1_w = (const float*)d_in[25];
    const float* n1_b = (const float*)d_in[26];
    const float* n2_w = (const float*)d_in[27];
    const float* n2_b = (const float*)d_in[28];
    const float* n3_w = (const float*)d_in[29];
    const float* n3_b = (const float*)d_in[30];
    const float* n4_w = (const float*)d_in[31];
    const float* n4_b = (const float*)d_in[32];
    const float* lin1_w = (const float*)d_in[33];
    const float* lin1_b = (const float*)d_in[34];
    const float* lin2_w = (const float*)d_in[35];
    const float* lin2_b = (const float*)d_in[36];
    const float* lin3_w = (const float*)d_in[37];
    const float* lin3_b = (const float*)d_in[38];

    // ---- output slices (out, tv, ta, vloc, vattn, aloc, aattn)
    float* out_main  = (float*)d_out;
    float* out_tv    = out_main + (size_t)TOK * 256;
    float* out_ta    = out_tv   + (size_t)TOK * 256;
    float* out_vloc  = out_ta   + (size_t)TOK * 256;
    float* out_vattn = out_vloc + (size_t)TOK * 128;
    float* out_aloc  = out_vattn+ (size_t)TOK * 128;
    float* out_aattn = out_aloc + (size_t)TOK * 128;

    // ---- workspace (bytes)
    char* base = (char*)d_ws;
    const size_t MB = 1024 * 1024;
    unsigned short* f_qkh = (unsigned short*)(base + 0);        // 8MB  [0,8)
    unsigned short* f_vh  = (unsigned short*)(base + 8*MB);     // 4MB  [8,12)
    unsigned short* f_o   = (unsigned short*)(base + 12*MB);    // 4MB  [12,16)
    unsigned short* f_samp= (unsigned short*)(base + 0);        // 8MB  [0,8)   (after attn)
    unsigned short* f_cat = (unsigned short*)(base + 8*MB);     // 8MB  [8,16)  (after attn)
    unsigned short* f_ffh = (unsigned short*)(base + 16*MB);    // 16MB [16,32)
    float* f_t = (float*)(base + 32*MB);                        // 8MB
    float* f_x = (float*)(base + 40*MB);                        // 8MB
    unsigned short* f_val = (unsigned short*)(base + 48*MB);    // 240MB (2*VROWS x 256)
    unsigned short* wb = (unsigned short*)(base + 300*MB);      // 2.125MB bf16 weights
    unsigned short* w_sa_in  = wb;                    // 768*256
    unsigned short* w_sa_out = w_sa_in  + 768 * 256;
    unsigned short* w_oa     = w_sa_out + 256 * 256;  // off|attn
    unsigned short* w_val    = w_oa     + 256 * 256;
    unsigned short* w_caout  = w_val    + 256 * 256;
    unsigned short* w_lin3   = w_caout  + 256 * 256;
    unsigned short* w_lin1   = w_lin3   + 256 * 512;
    unsigned short* w_lin2   = w_lin1   + 1024 * 256;
    float* bias_oa = (float*)(w_lin2 + 256 * 1024);

    // 1. all weight conversions + bias concat (one launch)
    WcArgs wa;
    wa.src[0] = sa_in_w;  wa.src[1] = sa_out_w; wa.src[2] = ca_off_w;
    wa.src[3] = ca_attn_w;wa.src[4] = ca_val_w; wa.src[5] = ca_out_w;
    wa.src[6] = lin3_w;   wa.src[7] = lin1_w;   wa.src[8] = lin2_w;
    hipLaunchKernelGGL(wconv_kernel, dim3(1089), dim3(256), 0, stream,
                       wa, wb, ca_off_b, ca_attn_b, bias_oa);

    // 2. qk = (tgt+qpos) @ sa_in[0:512]^T -> bf16
    hipLaunchKernelGGL((gemm_mfma_kernel<64,128,false,false,true,true,false>),
                       dim3(128, 4), dim3(512), 0, stream,
                       tgt, nullptr, query_pos, w_sa_in, sa_in_b, f_qkh,
                       TOK, 512, 256, 0);
    // 3. v = tgt @ sa_in[512:768]^T -> bf16
    hipLaunchKernelGGL((gemm_mfma_kernel<64,128,false,false,true,false,false>),
                       dim3(128, 2), dim3(512), 0, stream,
                       tgt, nullptr, nullptr, w_sa_in + (size_t)512 * 256,
                       sa_in_b + 512, f_vh, TOK, 256, 256, 0);
    // 4. flash attention
    hipLaunchKernelGGL(sa_flash_kernel, dim3(Bb * 32), dim3(256), 0, stream,
                       f_qkh, f_vh, f_o);
    // 5. t = LN(tgt + o @ sa_out^T, n2)   [fused]
    hipLaunchKernelGGL((gemm_ln_kernel<32,false>), dim3(256), dim3(512), 0, stream,
                       f_o, w_sa_out, sa_out_b, tgt, n2_w, n2_b,
                       f_t, nullptr, TOK, 256);
    // 6. oa GEMM + msda prep -> vloc/vattn/aloc/aattn  [fused]
    hipLaunchKernelGGL(gemm_prep_kernel, dim3(128), dim3(512), 0, stream,
                       f_t, query_pos, w_oa, bias_oa, ref_v, ref_a,
                       out_vloc, out_vattn, out_aloc, out_aattn);
    // 7. combined val projection (video rows then audio rows) -> bf16
    //    v1 structure + 2-deep k-chunk prefetch.
    hipLaunchKernelGGL(val_stream_kernel, dim3(2 * VROWS / 256), dim3(1024), 0, stream,
                       video_src, audio_src, w_val, ca_val_b, f_val);
    // 8. combined sampling -> f_samp[16384][256] bf16
    hipLaunchKernelGGL(msda_sample_kernel, dim3(2 * TOK / 4), dim3(256), 0, stream,
                       f_val, out_vloc, out_vattn, out_aloc, out_aattn, f_samp);
    // 9. tv/ta = LN(t + samp @ ca_out^T, n1)  [fused, dual]
    hipLaunchKernelGGL((gemm_ln_kernel<64,true>), dim3(256), dim3(512), 0, stream,
                       f_samp, w_caout, ca_out_b, f_t, n1_w, n1_b,
                       out_tv, out_ta, 2 * TOK, 256);
    // 10. cat = LN(concat(tv,ta), n4) -> bf16
    hipLaunchKernelGGL(cat_ln_kernel, dim3(TOK), dim3(256), 0, stream,
                       out_tv, out_ta, n4_w, n4_b, f_cat);
    // 11. x = relu(cat @ lin3^T + b) -> fp32
    hipLaunchKernelGGL((gemm_mfma_kernel<64,128,true,true,false,false,false>),
                       dim3(128, 2), dim3(512), 0, stream,
                       f_cat, nullptr, nullptr, w_lin3, lin3_b, f_x,
                       TOK, 256, 512, 0);
    // 12. ffh = relu(x @ lin1^T + b) -> bf16
    hipLaunchKernelGGL((gemm_mfma_kernel<128,256,true,false,true,false,false>),
                       dim3(64, 4), dim3(512), 0, stream,
                       f_x, nullptr, nullptr, w_lin1, lin1_b, f_ffh,
                       TOK, 1024, 256, 0);
    // 13. out = LN(x + ffh @ lin2^T, n3)  [fused]
    hipLaunchKernelGGL((gemm_ln_kernel<32,false>), dim3(256), dim3(512), 0, stream,
                       f_ffh, w_lin2, lin2_b, f_x, n3_w, n3_b,
                       out_main, nullptr, TOK, 1024);
}